// Round 5
// baseline (427.591 us; speedup 1.0000x reference)
//
#include <hip/hip_runtime.h>
#include <math.h>

#define Bn 8
#define Nn 1024
#define Cn 1024
#define Hn 16
#define Dn 64
#define HIDn 4096
#define SCALEf 0.125f

typedef __bf16 bf16x8 __attribute__((ext_vector_type(8)));
typedef float f32x4 __attribute__((ext_vector_type(4)));

__device__ inline unsigned short f2bf(float f) {
    union { float f; unsigned int u; } v; v.f = f;
    unsigned int r = v.u + 0x7fffu + ((v.u >> 16) & 1u);
    return (unsigned short)(r >> 16);
}

__device__ inline void gload_lds16(const void* g, void* l) {
    auto gp = reinterpret_cast<const unsigned int __attribute__((address_space(1)))*>(
        reinterpret_cast<uintptr_t>(g));
    auto lp = reinterpret_cast<unsigned int __attribute__((address_space(3)))*>(
        reinterpret_cast<uintptr_t>(l));
    __builtin_amdgcn_global_load_lds(gp, lp, 16, 0, 0);
}

// ---------------- f32 -> bf16 conversion ----------------
__global__ __launch_bounds__(256) void cvt_bf16(const float* __restrict__ in,
                                                unsigned short* __restrict__ out, int n4) {
    int i = blockIdx.x * 256 + threadIdx.x;
    if (i < n4) {
        float4 v = ((const float4*)in)[i];
        ushort4 o;
        o.x = f2bf(v.x); o.y = f2bf(v.y); o.z = f2bf(v.z); o.w = f2bf(v.w);
        ((ushort4*)out)[i] = o;
    }
}

// ---------------- LayerNorm (C=1024), fp32 in -> bf16 out ----------------
__global__ __launch_bounds__(256) void ln_kernel(const float* __restrict__ x,
                                                 const float* __restrict__ g,
                                                 const float* __restrict__ bb,
                                                 unsigned short* __restrict__ out) {
    const int row = blockIdx.x;
    const int tid = threadIdx.x;
    const float4 v = ((const float4*)(x + (size_t)row * 1024))[tid];
    float s = v.x + v.y + v.z + v.w;
    float q = v.x * v.x + v.y * v.y + v.z * v.z + v.w * v.w;
#pragma unroll
    for (int d = 1; d < 64; d <<= 1) {
        s += __shfl_xor(s, d, 64);
        q += __shfl_xor(q, d, 64);
    }
    __shared__ float ss[4], sq[4];
    const int wv = tid >> 6;
    if ((tid & 63) == 0) { ss[wv] = s; sq[wv] = q; }
    __syncthreads();
    s = ss[0] + ss[1] + ss[2] + ss[3];
    q = sq[0] + sq[1] + sq[2] + sq[3];
    const float mu = s * (1.0f / 1024.0f);
    const float var = q * (1.0f / 1024.0f) - mu * mu;
    const float rs = rsqrtf(var + 1e-5f);
    const int c = tid * 4;
    ushort4 o;
    o.x = f2bf((v.x - mu) * rs * g[c + 0] + bb[c + 0]);
    o.y = f2bf((v.y - mu) * rs * g[c + 1] + bb[c + 1]);
    o.z = f2bf((v.z - mu) * rs * g[c + 2] + bb[c + 2]);
    o.w = f2bf((v.w - mu) * rs * g[c + 3] + bb[c + 3]);
    *(ushort4*)&out[(size_t)row * 1024 + c] = o;
}

// ---------------- GEMM v4: phase-split schedule (T3+T4+T5 on top of T1+T2) ----
// C[M,N] = A[M,K] * Bw[N,K]^T, tile 256xBN, BK=64, 8 waves (512 thr), dbuf LDS.
// Per K-tile: 4 phases (BN=256) / 2 phases (BN=128); each phase =
//   {ds_read frags | half-tile gload_lds issue} -> s_barrier -> lgkmcnt(0) ->
//   setprio(1) -> 16 MFMA -> setprio(0) -> s_barrier.
// Tile t+1 staged during t's phases 0-1; single vmcnt(0) at end of tile t
// (nothing younger in flight) -> loads span ~4 phases / 6 barriers.
// MODE 0: out bf16. MODE 1: out f32 = acc+bias[n]+res. MODE 2: bf16 gelu(acc+bias).

#define PH_READ_A(mh, kk)                                                              \
    _Pragma("unroll") for (int i = 0; i < 4; ++i) {                                    \
        const int r = wm * (MFM * 16) + ((mh) * 4 + i) * 16 + fr;                      \
        afr[i] = *(const bf16x8*)(As + r * 64 + ((((kk) * 4 + kg) ^ (r & 7)) * 8));    \
    }

#define PH_READ_B(kk)                                                                  \
    _Pragma("unroll") for (int nt = 0; nt < 4; ++nt) {                                 \
        const int r = wn * 64 + nt * 16 + fr;                                          \
        bfr[nt] = *(const bf16x8*)(Bs + r * 64 + ((((kk) * 4 + kg) ^ (r & 7)) * 8));   \
    }

#define PH_MFMA(mh)                                                                    \
    asm volatile("s_waitcnt lgkmcnt(0)" ::: "memory");                                 \
    __builtin_amdgcn_sched_barrier(0);                                                 \
    __builtin_amdgcn_s_setprio(1);                                                     \
    _Pragma("unroll") for (int i = 0; i < 4; ++i)                                      \
        _Pragma("unroll") for (int nt = 0; nt < 4; ++nt)                               \
            acc[(mh) * 4 + i][nt] = __builtin_amdgcn_mfma_f32_16x16x32_bf16(           \
                bfr[nt], afr[i], acc[(mh) * 4 + i][nt], 0, 0, 0);                      \
    __builtin_amdgcn_s_setprio(0);                                                     \
    __builtin_amdgcn_sched_barrier(0);

template <int MODE, int BN>
__global__ __launch_bounds__(512, 2) void gemm8(const unsigned short* __restrict__ A,
                                                const unsigned short* __restrict__ Bw,
                                                void* __restrict__ Out,
                                                const float* __restrict__ bias,
                                                const float* __restrict__ res,
                                                int M, int N, int K, int gn) {
    constexpr int WN = BN / 64;         // waves along N: 4 (BN=256) or 2 (BN=128)
    constexpr int WM = 8 / WN;          // waves along M: 2 or 4
    constexpr int MFM = 256 / WM / 16;  // m-frags per wave: 8 or 4
    constexpr int RB = BN / 64;         // B stage rounds
    constexpr int ASZ = 256 * 64;
    constexpr int BSZ = BN * 64;
    __shared__ unsigned short lds[2 * (ASZ + BSZ)];

    const int tid = threadIdx.x;
    const int l = tid & 63, w = tid >> 6;
    const int nwg = gridDim.x;
    const int sw = (blockIdx.x & 7) * (nwg >> 3) + (blockIdx.x >> 3);  // XCD swizzle
    const int m0 = (sw / gn) * 256;
    const int n0 = (sw % gn) * BN;
    const int wm = w / WN, wn = w % WN;
    const int fr = l & 15, kg = l >> 4;
    const int sr = l >> 3, sslot = l & 7;

    auto stageA = [&](int bufi, int k0) {
        unsigned short* dA = lds + bufi * (ASZ + BSZ);
#pragma unroll
        for (int j = 0; j < 4; ++j) {
            const int r = j * 64 + w * 8 + sr;
            gload_lds16(A + (size_t)(m0 + r) * K + k0 + ((sslot ^ (r & 7)) * 8),
                        dA + (j * 64 + w * 8) * 64);
        }
    };
    auto stageB = [&](int bufi, int k0) {
        unsigned short* dB = lds + bufi * (ASZ + BSZ) + ASZ;
#pragma unroll
        for (int j = 0; j < RB; ++j) {
            const int r = j * 64 + w * 8 + sr;
            gload_lds16(Bw + (size_t)(n0 + r) * K + k0 + ((sslot ^ (r & 7)) * 8),
                        dB + (j * 64 + w * 8) * 64);
        }
    };

    f32x4 acc[MFM][4] = {};

    const int NT = K >> 6;
    int cur = 0;
    stageA(0, 0);
    stageB(0, 0);
    asm volatile("s_waitcnt vmcnt(0)" ::: "memory");
    __builtin_amdgcn_sched_barrier(0);
    __builtin_amdgcn_s_barrier();

    for (int t = 0; t < NT; ++t) {
        const unsigned short* As = lds + cur * (ASZ + BSZ);
        const unsigned short* Bs = As + ASZ;
        const bool pre = (t + 1 < NT);
        const int nk0 = (t + 1) << 6;
        bf16x8 afr[4], bfr[4];

        if constexpr (BN == 256) {
            // P0: (mh0, kk0)
            PH_READ_A(0, 0); PH_READ_B(0);
            if (pre) stageA(cur ^ 1, nk0);
            __builtin_amdgcn_s_barrier();
            PH_MFMA(0);
            __builtin_amdgcn_s_barrier();
            // P1: (mh1, kk0)
            PH_READ_A(1, 0);
            if (pre) stageB(cur ^ 1, nk0);
            __builtin_amdgcn_s_barrier();
            PH_MFMA(1);
            __builtin_amdgcn_s_barrier();
            // P2: (mh0, kk1)
            PH_READ_A(0, 1); PH_READ_B(1);
            __builtin_amdgcn_s_barrier();
            PH_MFMA(0);
            __builtin_amdgcn_s_barrier();
            // P3: (mh1, kk1)
            PH_READ_A(1, 1);
            __builtin_amdgcn_s_barrier();
            PH_MFMA(1);
            if (pre) { asm volatile("s_waitcnt vmcnt(0)" ::: "memory"); }
            __builtin_amdgcn_sched_barrier(0);
            __builtin_amdgcn_s_barrier();
        } else {
            // P0: kk0
            PH_READ_A(0, 0); PH_READ_B(0);
            if (pre) stageA(cur ^ 1, nk0);
            __builtin_amdgcn_s_barrier();
            PH_MFMA(0);
            __builtin_amdgcn_s_barrier();
            // P1: kk1
            PH_READ_A(0, 1); PH_READ_B(1);
            if (pre) stageB(cur ^ 1, nk0);
            __builtin_amdgcn_s_barrier();
            PH_MFMA(0);
            if (pre) { asm volatile("s_waitcnt vmcnt(0)" ::: "memory"); }
            __builtin_amdgcn_sched_barrier(0);
            __builtin_amdgcn_s_barrier();
        }
        cur ^= 1;
    }

    // Epilogue: lane (fr,kg) reg r holds C[m = base+mt*16+fr][n = base+nt*16+kg*4+r]
    const int cq = kg * 4;
#pragma unroll
    for (int mt = 0; mt < MFM; ++mt) {
        const int row = m0 + wm * (MFM * 16) + mt * 16 + fr;
#pragma unroll
        for (int nt = 0; nt < 4; ++nt) {
            const int col = n0 + wn * 64 + nt * 16 + cq;
            const f32x4 a = acc[mt][nt];
            if (MODE == 0) {
                ushort4 o;
                o.x = f2bf(a[0]); o.y = f2bf(a[1]); o.z = f2bf(a[2]); o.w = f2bf(a[3]);
                *(ushort4*)&((unsigned short*)Out)[(size_t)row * N + col] = o;
            } else if (MODE == 1) {
                const float4 bi = *(const float4*)&bias[col];
                const float4 re = *(const float4*)&res[(size_t)row * N + col];
                float4 o;
                o.x = a[0] + bi.x + re.x; o.y = a[1] + bi.y + re.y;
                o.z = a[2] + bi.z + re.z; o.w = a[3] + bi.w + re.w;
                *(float4*)&((float*)Out)[(size_t)row * N + col] = o;
            } else {
                const float4 bi = *(const float4*)&bias[col];
                float t0 = a[0] + bi.x, t1 = a[1] + bi.y, t2 = a[2] + bi.z, t3 = a[3] + bi.w;
                ushort4 o;
                o.x = f2bf(0.5f * t0 * (1.0f + erff(t0 * 0.70710678118654752f)));
                o.y = f2bf(0.5f * t1 * (1.0f + erff(t1 * 0.70710678118654752f)));
                o.z = f2bf(0.5f * t2 * (1.0f + erff(t2 * 0.70710678118654752f)));
                o.w = f2bf(0.5f * t3 * (1.0f + erff(t3 * 0.70710678118654752f)));
                *(ushort4*)&((unsigned short*)Out)[(size_t)row * N + col] = o;
            }
        }
    }
}

// ---------------- Flash attention (unchanged) ----------------
__global__ __launch_bounds__(256) void attn_kernel(const unsigned short* __restrict__ qkv,
                                                   const int* __restrict__ length,
                                                   unsigned short* __restrict__ y) {
    const int id2 = (blockIdx.x & 7) * 256 + (blockIdx.x >> 3);
    const int qt = id2 & 15;
    const int h = (id2 >> 4) & 15;
    const int b = id2 >> 8;
    const int tid = threadIdx.x, lane = tid & 63, w = tid >> 6;
    const int q0 = qt * 64;
    const int len = length[b];
    const int ntiles = (len + 63) >> 6;

    __shared__ unsigned short Ks[64 * 64];
    __shared__ unsigned short Vs[64 * 64];
    __shared__ unsigned short Ps[4 * 16 * 64];

    const int fr = lane & 15, kg = lane >> 4;

    bf16x8 qf[2];
    {
        const unsigned short* qb = qkv + (size_t)(b * Nn + q0 + w * 16 + fr) * 3072 + h * 64 + kg * 8;
        qf[0] = *(const bf16x8*)(qb);
        qf[1] = *(const bf16x8*)(qb + 32);
    }

    float m[4] = {-1e30f, -1e30f, -1e30f, -1e30f};
    float lsum[4] = {0.f, 0.f, 0.f, 0.f};
    f32x4 accO[4] = {};

    const int krow_l = lane >> 3;
    const int kslot = lane & 7;
    const int vk0 = (tid >> 3) * 2;
    const int vd0 = (tid & 7) * 8;
    const unsigned short* vbase = qkv + (size_t)(b * Nn) * 3072 + 2048 + h * 64 + vd0;

    for (int t = 0; t < ntiles; ++t) {
        const int kv0 = t << 6;
#pragma unroll
        for (int c = 0; c < 2; ++c) {
            const int k = c * 32 + w * 8 + krow_l;
            const int ss = kslot ^ ((k ^ (k >> 3)) & 7);
            gload_lds16(qkv + (size_t)(b * Nn + kv0 + k) * 3072 + 1024 + h * 64 + ss * 8,
                        &Ks[(c * 32 + w * 8) * 64]);
        }
        {
            uint4 v0 = *(const uint4*)(vbase + (size_t)(kv0 + vk0) * 3072);
            uint4 v1 = *(const uint4*)(vbase + (size_t)(kv0 + vk0 + 1) * 3072);
            const unsigned* a0 = (const unsigned*)&v0;
            const unsigned* a1 = (const unsigned*)&v1;
#pragma unroll
            for (int i = 0; i < 8; ++i) {
                const unsigned lo = (a0[i >> 1] >> ((i & 1) * 16)) & 0xffffu;
                const unsigned hi = (a1[i >> 1] >> ((i & 1) * 16)) & 0xffffu;
                const int d = vd0 + i;
                const int off = (d * 128 + vk0 * 2) ^ (((d ^ (d >> 3)) & 7) << 4);
                *(unsigned*)((char*)Vs + off) = lo | (hi << 16);
            }
        }
        __syncthreads();

        f32x4 accS[4] = {};
#pragma unroll
        for (int nt = 0; nt < 4; ++nt) {
            const int kr = nt * 16 + fr;
            const int swz = ((kr ^ (kr >> 3)) & 7) << 4;
#pragma unroll
            for (int kt = 0; kt < 2; ++kt) {
                bf16x8 kf = *(const bf16x8*)((const char*)Ks + ((kr * 128 + (kt * 32 + kg * 8) * 2) ^ swz));
                accS[nt] = __builtin_amdgcn_mfma_f32_16x16x32_bf16(qf[kt], kf, accS[nt], 0, 0, 0);
            }
        }

        float p[4][4], sc[4];
#pragma unroll
        for (int r = 0; r < 4; ++r) {
            float sv[4];
            float mx = -1e30f;
#pragma unroll
            for (int nt = 0; nt < 4; ++nt) {
                sv[nt] = accS[nt][r] * SCALEf + ((kv0 + nt * 16 + fr >= len) ? -10000.0f : 0.0f);
                mx = fmaxf(mx, sv[nt]);
            }
#pragma unroll
            for (int d = 1; d < 16; d <<= 1) mx = fmaxf(mx, __shfl_xor(mx, d, 64));
            const float mnew = fmaxf(m[r], mx);
            sc[r] = __expf(m[r] - mnew);
            float rsum = 0.f;
#pragma unroll
            for (int nt = 0; nt < 4; ++nt) {
                p[nt][r] = __expf(sv[nt] - mnew);
                rsum += p[nt][r];
            }
#pragma unroll
            for (int d = 1; d < 16; d <<= 1) rsum += __shfl_xor(rsum, d, 64);
            lsum[r] = lsum[r] * sc[r] + rsum;
            m[r] = mnew;
        }
#pragma unroll
        for (int nd = 0; nd < 4; ++nd)
#pragma unroll
            for (int r = 0; r < 4; ++r) accO[nd][r] *= sc[r];

#pragma unroll
        for (int r = 0; r < 4; ++r) {
            const int q = kg * 4 + r;
            const int swz = ((q ^ (q >> 3)) & 7) << 4;
#pragma unroll
            for (int nt = 0; nt < 4; ++nt) {
                const int kk = nt * 16 + fr;
                *(unsigned short*)((char*)Ps + ((w * 2048 + q * 128 + kk * 2) ^ swz)) = f2bf(p[nt][r]);
            }
        }
        __builtin_amdgcn_wave_barrier();

        const int swzp = ((fr ^ (fr >> 3)) & 7) << 4;
#pragma unroll
        for (int kt = 0; kt < 2; ++kt) {
            bf16x8 pf = *(const bf16x8*)((const char*)Ps +
                        ((w * 2048 + fr * 128 + (kt * 32 + kg * 8) * 2) ^ swzp));
#pragma unroll
            for (int nd = 0; nd < 4; ++nd) {
                const int d = nd * 16 + fr;
                const int swzv = ((d ^ (d >> 3)) & 7) << 4;
                bf16x8 vf = *(const bf16x8*)((const char*)Vs +
                            ((d * 128 + (kt * 32 + kg * 8) * 2) ^ swzv));
                accO[nd] = __builtin_amdgcn_mfma_f32_16x16x32_bf16(pf, vf, accO[nd], 0, 0, 0);
            }
        }
        __syncthreads();
    }

#pragma unroll
    for (int r = 0; r < 4; ++r) {
        const float inv = 1.0f / lsum[r];
        const int row = q0 + w * 16 + kg * 4 + r;
#pragma unroll
        for (int nd = 0; nd < 4; ++nd)
            y[(size_t)(b * Nn + row) * 1024 + h * 64 + nd * 16 + fr] = f2bf(accO[nd][r] * inv);
    }
}

// ---------------- launch ----------------
extern "C" void kernel_launch(void* const* d_in, const int* in_sizes, int n_in,
                              void* d_out, int out_size, void* d_ws, size_t ws_size,
                              hipStream_t stream) {
    (void)in_sizes; (void)n_in; (void)out_size; (void)ws_size;
    const float* x     = (const float*)d_in[0];
    const int*   len   = (const int*)d_in[1];
    const float* g1    = (const float*)d_in[2];
    const float* b1    = (const float*)d_in[3];
    const float* Wqkv  = (const float*)d_in[4];
    const float* Wproj = (const float*)d_in[5];
    const float* bproj = (const float*)d_in[6];
    const float* g2    = (const float*)d_in[7];
    const float* b2    = (const float*)d_in[8];
    const float* W1    = (const float*)d_in[9];
    const float* bb1   = (const float*)d_in[10];
    const float* W2    = (const float*)d_in[11];
    const float* bb2   = (const float*)d_in[12];
    float* out = (float*)d_out;

    char* ws = (char*)d_ws;
    size_t off = 0;
    auto alloc = [&](size_t bytes) {
        void* p = ws + off;
        off += (bytes + 255) & ~(size_t)255;
        return p;
    };
    unsigned short* xn  = (unsigned short*)alloc(8192ULL * 1024 * 2);
    unsigned short* qkv = (unsigned short*)alloc(8192ULL * 3072 * 2);
    unsigned short* yb  = (unsigned short*)alloc(8192ULL * 1024 * 2);
    float* x2           = (float*)alloc(8192ULL * 1024 * 4);
    unsigned short* wqkv_b  = (unsigned short*)alloc(3072ULL * 1024 * 2);
    unsigned short* wproj_b = (unsigned short*)alloc(1024ULL * 1024 * 2);
    unsigned short* w1_b    = (unsigned short*)alloc(4096ULL * 1024 * 2);
    unsigned short* w2_b    = (unsigned short*)alloc(1024ULL * 4096 * 2);
    unsigned short* hb = qkv;  // reuse: qkv+yb dead by MLP1

    cvt_bf16<<<3072 * 1024 / 4 / 256, 256, 0, stream>>>(Wqkv, wqkv_b, 3072 * 1024 / 4);
    cvt_bf16<<<1024 * 1024 / 4 / 256, 256, 0, stream>>>(Wproj, wproj_b, 1024 * 1024 / 4);
    cvt_bf16<<<4096 * 1024 / 4 / 256, 256, 0, stream>>>(W1, w1_b, 4096 * 1024 / 4);
    cvt_bf16<<<4096 * 1024 / 4 / 256, 256, 0, stream>>>(W2, w2_b, 4096 * 1024 / 4);

    ln_kernel<<<8192, 256, 0, stream>>>(x, g1, b1, xn);
    gemm8<0, 128><<<768, 512, 0, stream>>>(xn, wqkv_b, qkv, nullptr, nullptr, 8192, 3072, 1024, 24);
    attn_kernel<<<2048, 256, 0, stream>>>(qkv, len, yb);
    gemm8<1, 128><<<256, 512, 0, stream>>>(yb, wproj_b, x2, bproj, x, 8192, 1024, 1024, 8);
    ln_kernel<<<8192, 256, 0, stream>>>(x2, g2, b2, xn);
    gemm8<2, 256><<<512, 512, 0, stream>>>(xn, w1_b, hb, bb1, nullptr, 8192, 4096, 1024, 16);
    gemm8<1, 128><<<256, 512, 0, stream>>>(hb, w2_b, out, bb2, x2, 8192, 1024, 4096, 8);
}

// Round 6
// 407.720 us; speedup vs baseline: 1.0487x; 1.0487x over previous
//
#include <hip/hip_runtime.h>
#include <math.h>

#define Bn 8
#define Nn 1024
#define Cn 1024
#define Hn 16
#define Dn 64
#define HIDn 4096
#define SCALEf 0.125f

typedef __bf16 bf16x8 __attribute__((ext_vector_type(8)));
typedef float f32x4 __attribute__((ext_vector_type(4)));

__device__ inline unsigned short f2bf(float f) {
    union { float f; unsigned int u; } v; v.f = f;
    unsigned int r = v.u + 0x7fffu + ((v.u >> 16) & 1u);
    return (unsigned short)(r >> 16);
}

__device__ inline void gload_lds16(const void* g, void* l) {
    auto gp = reinterpret_cast<const unsigned int __attribute__((address_space(1)))*>(
        reinterpret_cast<uintptr_t>(g));
    auto lp = reinterpret_cast<unsigned int __attribute__((address_space(3)))*>(
        reinterpret_cast<uintptr_t>(l));
    __builtin_amdgcn_global_load_lds(gp, lp, 16, 0, 0);
}

// ---------------- f32 -> bf16 conversion ----------------
__global__ __launch_bounds__(256) void cvt_bf16(const float* __restrict__ in,
                                                unsigned short* __restrict__ out, int n4) {
    int i = blockIdx.x * 256 + threadIdx.x;
    if (i < n4) {
        float4 v = ((const float4*)in)[i];
        ushort4 o;
        o.x = f2bf(v.x); o.y = f2bf(v.y); o.z = f2bf(v.z); o.w = f2bf(v.w);
        ((ushort4*)out)[i] = o;
    }
}

// ---------------- LayerNorm (C=1024), fp32 in -> bf16 out ----------------
__global__ __launch_bounds__(256) void ln_kernel(const float* __restrict__ x,
                                                 const float* __restrict__ g,
                                                 const float* __restrict__ bb,
                                                 unsigned short* __restrict__ out) {
    const int row = blockIdx.x;
    const int tid = threadIdx.x;
    const float4 v = ((const float4*)(x + (size_t)row * 1024))[tid];
    float s = v.x + v.y + v.z + v.w;
    float q = v.x * v.x + v.y * v.y + v.z * v.z + v.w * v.w;
#pragma unroll
    for (int d = 1; d < 64; d <<= 1) {
        s += __shfl_xor(s, d, 64);
        q += __shfl_xor(q, d, 64);
    }
    __shared__ float ss[4], sq[4];
    const int wv = tid >> 6;
    if ((tid & 63) == 0) { ss[wv] = s; sq[wv] = q; }
    __syncthreads();
    s = ss[0] + ss[1] + ss[2] + ss[3];
    q = sq[0] + sq[1] + sq[2] + sq[3];
    const float mu = s * (1.0f / 1024.0f);
    const float var = q * (1.0f / 1024.0f) - mu * mu;
    const float rs = rsqrtf(var + 1e-5f);
    const int c = tid * 4;
    ushort4 o;
    o.x = f2bf((v.x - mu) * rs * g[c + 0] + bb[c + 0]);
    o.y = f2bf((v.y - mu) * rs * g[c + 1] + bb[c + 1]);
    o.z = f2bf((v.z - mu) * rs * g[c + 2] + bb[c + 2]);
    o.w = f2bf((v.w - mu) * rs * g[c + 3] + bb[c + 3]);
    *(ushort4*)&out[(size_t)row * 1024 + c] = o;
}

// ---------------- GEMM v5: quarter-granular counted pipeline (true T3+T4) ----
// C[M,N] = A[M,K] * Bw[N,K]^T, tile 256xBN, BK=64, 8 waves, dbuf LDS.
// K-tile cut into 4 quarters: Q0=B(kk0) Q1=A(kk0) Q2=B(kk1) Q3=A(kk1),
// one quarter issued per phase, consumed 4 phases later. vmcnt NEVER drains
// in steady state (waits 6/4/6/4 for BN=256, 3/3 for BN=128; <=8 loads in
// flight spanning ~4 barriers). One s_barrier per phase (tile-level dbuf ->
// no write-after-read hazard). Quarter LDS layout [rows][32] with slot
// rotation (sg+(r>>1))&3 -> 2-way (free) ds_read_b128 conflicts; inverse
// rotation applied on the global source (gload_lds writes linearly).
// MODE 0: out bf16. MODE 1: out f32 = acc+bias[n]+res. MODE 2: bf16 gelu(acc+bias).

#define LGKM0                                            \
    asm volatile("s_waitcnt lgkmcnt(0)" ::: "memory");   \
    __builtin_amdgcn_sched_barrier(0)
#define VMC(n)                                           \
    asm volatile("s_waitcnt vmcnt(" #n ")" ::: "memory");\
    __builtin_amdgcn_sched_barrier(0)
#define PRIO_MFMA(mh)                                    \
    __builtin_amdgcn_s_setprio(1);                       \
    mf16(mh);                                            \
    __builtin_amdgcn_s_setprio(0);                       \
    __builtin_amdgcn_sched_barrier(0)

template <int MODE, int BN>
__global__ __launch_bounds__(512, 2) void gemmp(const unsigned short* __restrict__ A,
                                                const unsigned short* __restrict__ Bw,
                                                void* __restrict__ Out,
                                                const float* __restrict__ bias,
                                                const float* __restrict__ res,
                                                int M, int N, int K, int gn) {
    constexpr int WN = BN / 64, WM = 8 / WN, MFM = 256 / WM / 16;
    constexpr int AQ = 256 * 32;   // A quarter (ushorts)
    constexpr int BQ = BN * 32;    // B quarter
    constexpr int BUF = 2 * AQ + 2 * BQ;
    __shared__ unsigned short lds[2 * BUF];

    const int tid = threadIdx.x;
    const int l = tid & 63, w = tid >> 6;
    const int nwg = gridDim.x;
    const int sw = (blockIdx.x & 7) * (nwg >> 3) + (blockIdx.x >> 3);  // XCD swizzle
    const int m0 = (sw / gn) * 256;
    const int n0 = (sw % gn) * BN;
    const int wm = w / WN, wn = w % WN;
    const int fr = l & 15, kg = l >> 4;
    const int sgq = ((l & 3) - ((l >> 3) & 3)) & 3;  // inverse slot rotation (global side)
    const int srow = l >> 2;                          // row-in-16 for staging

    f32x4 acc[MFM][4] = {};
    bf16x8 afr[4], bfr[4];

    auto stA = [&](int bufi, int kk, int k0) {
#pragma unroll
        for (int j = 0; j < 2; ++j) {
            const int rb = w * 32 + j * 16;
            gload_lds16(A + (size_t)(m0 + rb + srow) * K + k0 + kk * 32 + sgq * 8,
                        lds + bufi * BUF + kk * AQ + rb * 32);
        }
    };
    auto stB = [&](int bufi, int kk, int k0) {
        if constexpr (BN == 256) {
#pragma unroll
            for (int j = 0; j < 2; ++j) {
                const int rb = w * 32 + j * 16;
                gload_lds16(Bw + (size_t)(n0 + rb + srow) * K + k0 + kk * 32 + sgq * 8,
                            lds + bufi * BUF + 2 * AQ + kk * BQ + rb * 32);
            }
        } else {
            const int rb = w * 16;
            gload_lds16(Bw + (size_t)(n0 + rb + srow) * K + k0 + kk * 32 + sgq * 8,
                        lds + bufi * BUF + 2 * AQ + kk * BQ + rb * 32);
        }
    };
    auto rdA = [&](int bufi, int kk, int mh) {
        const unsigned short* base = lds + bufi * BUF + kk * AQ;
#pragma unroll
        for (int i = 0; i < 4; ++i) {
            const int r = wm * (MFM * 16) + (mh * 4 + i) * 16 + fr;
            afr[i] = *(const bf16x8*)(base + r * 32 + (((kg + ((r >> 1) & 3)) & 3) * 8));
        }
    };
    auto rdB = [&](int bufi, int kk) {
        const unsigned short* base = lds + bufi * BUF + 2 * AQ + kk * BQ;
#pragma unroll
        for (int nt = 0; nt < 4; ++nt) {
            const int r = wn * 64 + nt * 16 + fr;
            bfr[nt] = *(const bf16x8*)(base + r * 32 + (((kg + ((r >> 1) & 3)) & 3) * 8));
        }
    };
    auto mf16 = [&](int mh) {
#pragma unroll
        for (int i = 0; i < 4; ++i)
#pragma unroll
            for (int nt = 0; nt < 4; ++nt)
                acc[mh * 4 + i][nt] = __builtin_amdgcn_mfma_f32_16x16x32_bf16(
                    bfr[nt], afr[i], acc[mh * 4 + i][nt], 0, 0, 0);
    };

    const int NT = K >> 6;
    int cur = 0;
    // prologue: issue all 4 quarters of tile 0 (FIFO order B0,A0,B1,A1)
    stB(0, 0, 0); stA(0, 0, 0); stB(0, 1, 0); stA(0, 1, 0);
    if constexpr (BN == 256) { VMC(4); } else { VMC(3); }
    __builtin_amdgcn_s_barrier();

    for (int t = 0; t < NT - 1; ++t) {
        const int nb = cur ^ 1;
        const int nk0 = (t + 1) << 6;
        if constexpr (BN == 256) {
            // P0: mh0,kk0 | issue B(t+1,kk0)
            stB(nb, 0, nk0); rdA(cur, 0, 0); rdB(cur, 0);
            LGKM0; PRIO_MFMA(0); VMC(6); __builtin_amdgcn_s_barrier();
            // P1: mh1,kk0 | issue A(t+1,kk0)
            stA(nb, 0, nk0); rdA(cur, 0, 1); rdB(cur, 0);
            LGKM0; PRIO_MFMA(1); VMC(4); __builtin_amdgcn_s_barrier();
            // P2: mh0,kk1 | issue B(t+1,kk1)
            stB(nb, 1, nk0); rdA(cur, 1, 0); rdB(cur, 1);
            LGKM0; PRIO_MFMA(0); VMC(6); __builtin_amdgcn_s_barrier();
            // P3: mh1,kk1 | issue A(t+1,kk1)
            stA(nb, 1, nk0); rdA(cur, 1, 1); rdB(cur, 1);
            LGKM0; PRIO_MFMA(1); VMC(4); __builtin_amdgcn_s_barrier();
        } else {
            // P0: kk0 | issue Q(t+1,0) = B+A(kk0)
            stB(nb, 0, nk0); stA(nb, 0, nk0); rdA(cur, 0, 0); rdB(cur, 0);
            LGKM0; PRIO_MFMA(0); VMC(3); __builtin_amdgcn_s_barrier();
            // P1: kk1 | issue Q(t+1,1)
            stB(nb, 1, nk0); stA(nb, 1, nk0); rdA(cur, 1, 0); rdB(cur, 1);
            LGKM0; PRIO_MFMA(0); VMC(3); __builtin_amdgcn_s_barrier();
        }
        cur ^= 1;
    }
    // tail tile (no issues; kk0 quarters ready; drain before kk1)
    if constexpr (BN == 256) {
        rdA(cur, 0, 0); rdB(cur, 0); LGKM0; PRIO_MFMA(0);
        rdA(cur, 0, 1);              LGKM0; PRIO_MFMA(1);
        VMC(0); __builtin_amdgcn_s_barrier();
        rdA(cur, 1, 0); rdB(cur, 1); LGKM0; PRIO_MFMA(0);
        rdA(cur, 1, 1);              LGKM0; PRIO_MFMA(1);
    } else {
        rdA(cur, 0, 0); rdB(cur, 0); LGKM0; PRIO_MFMA(0);
        VMC(0); __builtin_amdgcn_s_barrier();
        rdA(cur, 1, 0); rdB(cur, 1); LGKM0; PRIO_MFMA(0);
    }

    // Epilogue: lane (fr,kg) reg r holds C[m = base+mt*16+fr][n = base+nt*16+kg*4+r]
    const int cq = kg * 4;
#pragma unroll
    for (int mt = 0; mt < MFM; ++mt) {
        const int row = m0 + wm * (MFM * 16) + mt * 16 + fr;
#pragma unroll
        for (int nt = 0; nt < 4; ++nt) {
            const int col = n0 + wn * 64 + nt * 16 + cq;
            const f32x4 a = acc[mt][nt];
            if (MODE == 0) {
                ushort4 o;
                o.x = f2bf(a[0]); o.y = f2bf(a[1]); o.z = f2bf(a[2]); o.w = f2bf(a[3]);
                *(ushort4*)&((unsigned short*)Out)[(size_t)row * N + col] = o;
            } else if (MODE == 1) {
                const float4 bi = *(const float4*)&bias[col];
                const float4 re = *(const float4*)&res[(size_t)row * N + col];
                float4 o;
                o.x = a[0] + bi.x + re.x; o.y = a[1] + bi.y + re.y;
                o.z = a[2] + bi.z + re.z; o.w = a[3] + bi.w + re.w;
                *(float4*)&((float*)Out)[(size_t)row * N + col] = o;
            } else {
                const float4 bi = *(const float4*)&bias[col];
                float t0 = a[0] + bi.x, t1 = a[1] + bi.y, t2 = a[2] + bi.z, t3 = a[3] + bi.w;
                ushort4 o;
                o.x = f2bf(0.5f * t0 * (1.0f + erff(t0 * 0.70710678118654752f)));
                o.y = f2bf(0.5f * t1 * (1.0f + erff(t1 * 0.70710678118654752f)));
                o.z = f2bf(0.5f * t2 * (1.0f + erff(t2 * 0.70710678118654752f)));
                o.w = f2bf(0.5f * t3 * (1.0f + erff(t3 * 0.70710678118654752f)));
                *(ushort4*)&((unsigned short*)Out)[(size_t)row * N + col] = o;
            }
        }
    }
}

// ---------------- Flash attention (unchanged) ----------------
__global__ __launch_bounds__(256) void attn_kernel(const unsigned short* __restrict__ qkv,
                                                   const int* __restrict__ length,
                                                   unsigned short* __restrict__ y) {
    const int id2 = (blockIdx.x & 7) * 256 + (blockIdx.x >> 3);
    const int qt = id2 & 15;
    const int h = (id2 >> 4) & 15;
    const int b = id2 >> 8;
    const int tid = threadIdx.x, lane = tid & 63, w = tid >> 6;
    const int q0 = qt * 64;
    const int len = length[b];
    const int ntiles = (len + 63) >> 6;

    __shared__ unsigned short Ks[64 * 64];
    __shared__ unsigned short Vs[64 * 64];
    __shared__ unsigned short Ps[4 * 16 * 64];

    const int fr = lane & 15, kg = lane >> 4;

    bf16x8 qf[2];
    {
        const unsigned short* qb = qkv + (size_t)(b * Nn + q0 + w * 16 + fr) * 3072 + h * 64 + kg * 8;
        qf[0] = *(const bf16x8*)(qb);
        qf[1] = *(const bf16x8*)(qb + 32);
    }

    float m[4] = {-1e30f, -1e30f, -1e30f, -1e30f};
    float lsum[4] = {0.f, 0.f, 0.f, 0.f};
    f32x4 accO[4] = {};

    const int krow_l = lane >> 3;
    const int kslot = lane & 7;
    const int vk0 = (tid >> 3) * 2;
    const int vd0 = (tid & 7) * 8;
    const unsigned short* vbase = qkv + (size_t)(b * Nn) * 3072 + 2048 + h * 64 + vd0;

    for (int t = 0; t < ntiles; ++t) {
        const int kv0 = t << 6;
#pragma unroll
        for (int c = 0; c < 2; ++c) {
            const int k = c * 32 + w * 8 + krow_l;
            const int ss = kslot ^ ((k ^ (k >> 3)) & 7);
            gload_lds16(qkv + (size_t)(b * Nn + kv0 + k) * 3072 + 1024 + h * 64 + ss * 8,
                        &Ks[(c * 32 + w * 8) * 64]);
        }
        {
            uint4 v0 = *(const uint4*)(vbase + (size_t)(kv0 + vk0) * 3072);
            uint4 v1 = *(const uint4*)(vbase + (size_t)(kv0 + vk0 + 1) * 3072);
            const unsigned* a0 = (const unsigned*)&v0;
            const unsigned* a1 = (const unsigned*)&v1;
#pragma unroll
            for (int i = 0; i < 8; ++i) {
                const unsigned lo = (a0[i >> 1] >> ((i & 1) * 16)) & 0xffffu;
                const unsigned hi = (a1[i >> 1] >> ((i & 1) * 16)) & 0xffffu;
                const int d = vd0 + i;
                const int off = (d * 128 + vk0 * 2) ^ (((d ^ (d >> 3)) & 7) << 4);
                *(unsigned*)((char*)Vs + off) = lo | (hi << 16);
            }
        }
        __syncthreads();

        f32x4 accS[4] = {};
#pragma unroll
        for (int nt = 0; nt < 4; ++nt) {
            const int kr = nt * 16 + fr;
            const int swz = ((kr ^ (kr >> 3)) & 7) << 4;
#pragma unroll
            for (int kt = 0; kt < 2; ++kt) {
                bf16x8 kf = *(const bf16x8*)((const char*)Ks + ((kr * 128 + (kt * 32 + kg * 8) * 2) ^ swz));
                accS[nt] = __builtin_amdgcn_mfma_f32_16x16x32_bf16(qf[kt], kf, accS[nt], 0, 0, 0);
            }
        }

        float p[4][4], sc[4];
#pragma unroll
        for (int r = 0; r < 4; ++r) {
            float sv[4];
            float mx = -1e30f;
#pragma unroll
            for (int nt = 0; nt < 4; ++nt) {
                sv[nt] = accS[nt][r] * SCALEf + ((kv0 + nt * 16 + fr >= len) ? -10000.0f : 0.0f);
                mx = fmaxf(mx, sv[nt]);
            }
#pragma unroll
            for (int d = 1; d < 16; d <<= 1) mx = fmaxf(mx, __shfl_xor(mx, d, 64));
            const float mnew = fmaxf(m[r], mx);
            sc[r] = __expf(m[r] - mnew);
            float rsum = 0.f;
#pragma unroll
            for (int nt = 0; nt < 4; ++nt) {
                p[nt][r] = __expf(sv[nt] - mnew);
                rsum += p[nt][r];
            }
#pragma unroll
            for (int d = 1; d < 16; d <<= 1) rsum += __shfl_xor(rsum, d, 64);
            lsum[r] = lsum[r] * sc[r] + rsum;
            m[r] = mnew;
        }
#pragma unroll
        for (int nd = 0; nd < 4; ++nd)
#pragma unroll
            for (int r = 0; r < 4; ++r) accO[nd][r] *= sc[r];

#pragma unroll
        for (int r = 0; r < 4; ++r) {
            const int q = kg * 4 + r;
            const int swz = ((q ^ (q >> 3)) & 7) << 4;
#pragma unroll
            for (int nt = 0; nt < 4; ++nt) {
                const int kk = nt * 16 + fr;
                *(unsigned short*)((char*)Ps + ((w * 2048 + q * 128 + kk * 2) ^ swz)) = f2bf(p[nt][r]);
            }
        }
        __builtin_amdgcn_wave_barrier();

        const int swzp = ((fr ^ (fr >> 3)) & 7) << 4;
#pragma unroll
        for (int kt = 0; kt < 2; ++kt) {
            bf16x8 pf = *(const bf16x8*)((const char*)Ps +
                        ((w * 2048 + fr * 128 + (kt * 32 + kg * 8) * 2) ^ swzp));
#pragma unroll
            for (int nd = 0; nd < 4; ++nd) {
                const int d = nd * 16 + fr;
                const int swzv = ((d ^ (d >> 3)) & 7) << 4;
                bf16x8 vf = *(const bf16x8*)((const char*)Vs +
                            ((d * 128 + (kt * 32 + kg * 8) * 2) ^ swzv));
                accO[nd] = __builtin_amdgcn_mfma_f32_16x16x32_bf16(pf, vf, accO[nd], 0, 0, 0);
            }
        }
        __syncthreads();
    }

#pragma unroll
    for (int r = 0; r < 4; ++r) {
        const float inv = 1.0f / lsum[r];
        const int row = q0 + w * 16 + kg * 4 + r;
#pragma unroll
        for (int nd = 0; nd < 4; ++nd)
            y[(size_t)(b * Nn + row) * 1024 + h * 64 + nd * 16 + fr] = f2bf(accO[nd][r] * inv);
    }
}

// ---------------- launch ----------------
extern "C" void kernel_launch(void* const* d_in, const int* in_sizes, int n_in,
                              void* d_out, int out_size, void* d_ws, size_t ws_size,
                              hipStream_t stream) {
    (void)in_sizes; (void)n_in; (void)out_size; (void)ws_size;
    const float* x     = (const float*)d_in[0];
    const int*   len   = (const int*)d_in[1];
    const float* g1    = (const float*)d_in[2];
    const float* b1    = (const float*)d_in[3];
    const float* Wqkv  = (const float*)d_in[4];
    const float* Wproj = (const float*)d_in[5];
    const float* bproj = (const float*)d_in[6];
    const float* g2    = (const float*)d_in[7];
    const float* b2    = (const float*)d_in[8];
    const float* W1    = (const float*)d_in[9];
    const float* bb1   = (const float*)d_in[10];
    const float* W2    = (const float*)d_in[11];
    const float* bb2   = (const float*)d_in[12];
    float* out = (float*)d_out;

    char* ws = (char*)d_ws;
    size_t off = 0;
    auto alloc = [&](size_t bytes) {
        void* p = ws + off;
        off += (bytes + 255) & ~(size_t)255;
        return p;
    };
    unsigned short* xn  = (unsigned short*)alloc(8192ULL * 1024 * 2);
    unsigned short* qkv = (unsigned short*)alloc(8192ULL * 3072 * 2);
    unsigned short* yb  = (unsigned short*)alloc(8192ULL * 1024 * 2);
    float* x2           = (float*)alloc(8192ULL * 1024 * 4);
    unsigned short* wqkv_b  = (unsigned short*)alloc(3072ULL * 1024 * 2);
    unsigned short* wproj_b = (unsigned short*)alloc(1024ULL * 1024 * 2);
    unsigned short* w1_b    = (unsigned short*)alloc(4096ULL * 1024 * 2);
    unsigned short* w2_b    = (unsigned short*)alloc(1024ULL * 4096 * 2);
    unsigned short* hb = qkv;  // reuse: qkv+yb dead by MLP1

    cvt_bf16<<<3072 * 1024 / 4 / 256, 256, 0, stream>>>(Wqkv, wqkv_b, 3072 * 1024 / 4);
    cvt_bf16<<<1024 * 1024 / 4 / 256, 256, 0, stream>>>(Wproj, wproj_b, 1024 * 1024 / 4);
    cvt_bf16<<<4096 * 1024 / 4 / 256, 256, 0, stream>>>(W1, w1_b, 4096 * 1024 / 4);
    cvt_bf16<<<4096 * 1024 / 4 / 256, 256, 0, stream>>>(W2, w2_b, 4096 * 1024 / 4);

    ln_kernel<<<8192, 256, 0, stream>>>(x, g1, b1, xn);
    gemmp<0, 128><<<768, 512, 0, stream>>>(xn, wqkv_b, qkv, nullptr, nullptr, 8192, 3072, 1024, 24);
    attn_kernel<<<2048, 256, 0, stream>>>(qkv, len, yb);
    gemmp<1, 128><<<256, 512, 0, stream>>>(yb, wproj_b, x2, bproj, x, 8192, 1024, 1024, 8);
    ln_kernel<<<8192, 256, 0, stream>>>(x2, g2, b2, xn);
    gemmp<2, 256><<<512, 512, 0, stream>>>(xn, w1_b, hb, bb1, nullptr, 8192, 4096, 1024, 16);
    gemmp<1, 128><<<256, 512, 0, stream>>>(hb, w2_b, out, bb2, x2, 8192, 1024, 4096, 8);
}

// Round 7
// 398.453 us; speedup vs baseline: 1.0731x; 1.0233x over previous
//
#include <hip/hip_runtime.h>
#include <math.h>

#define Bn 8
#define Nn 1024
#define Cn 1024
#define Hn 16
#define Dn 64
#define HIDn 4096
#define SCALEf 0.125f

typedef __bf16 bf16x8 __attribute__((ext_vector_type(8)));
typedef float f32x4 __attribute__((ext_vector_type(4)));

__device__ inline unsigned short f2bf(float f) {
    union { float f; unsigned int u; } v; v.f = f;
    unsigned int r = v.u + 0x7fffu + ((v.u >> 16) & 1u);
    return (unsigned short)(r >> 16);
}

// exact-GELU via inlined Abramowitz-Stegun erf (|err|<=1.5e-7). No libm call:
// erff() is an OCML function CALL that forces spill/fill of the live 128-reg
// accumulator around ~128 calls/thread -- the R1-R6 MLP1 invariant bottleneck.
__device__ inline float gelu_exact(float x) {
    const float z = x * 0.70710678118654752f;
    const float az = fabsf(z);
    const float t = 1.0f / (1.0f + 0.3275911f * az);
    float poly = 0.254829592f +
                 t * (-0.284496736f +
                      t * (1.421413741f + t * (-1.453152027f + t * 1.061405429f)));
    poly *= t;
    const float e = __expf(-az * az);
    float erfv = 1.0f - poly * e;
    erfv = (z < 0.0f) ? -erfv : erfv;
    return 0.5f * x * (1.0f + erfv);
}

__device__ inline void gload_lds16(const void* g, void* l) {
    auto gp = reinterpret_cast<const unsigned int __attribute__((address_space(1)))*>(
        reinterpret_cast<uintptr_t>(g));
    auto lp = reinterpret_cast<unsigned int __attribute__((address_space(3)))*>(
        reinterpret_cast<uintptr_t>(l));
    __builtin_amdgcn_global_load_lds(gp, lp, 16, 0, 0);
}

// ---------------- f32 -> bf16 conversion ----------------
__global__ __launch_bounds__(256) void cvt_bf16(const float* __restrict__ in,
                                                unsigned short* __restrict__ out, int n4) {
    int i = blockIdx.x * 256 + threadIdx.x;
    if (i < n4) {
        float4 v = ((const float4*)in)[i];
        ushort4 o;
        o.x = f2bf(v.x); o.y = f2bf(v.y); o.z = f2bf(v.z); o.w = f2bf(v.w);
        ((ushort4*)out)[i] = o;
    }
}

// ---------------- LayerNorm (C=1024), fp32 in -> bf16 out ----------------
__global__ __launch_bounds__(256) void ln_kernel(const float* __restrict__ x,
                                                 const float* __restrict__ g,
                                                 const float* __restrict__ bb,
                                                 unsigned short* __restrict__ out) {
    const int row = blockIdx.x;
    const int tid = threadIdx.x;
    const float4 v = ((const float4*)(x + (size_t)row * 1024))[tid];
    float s = v.x + v.y + v.z + v.w;
    float q = v.x * v.x + v.y * v.y + v.z * v.z + v.w * v.w;
#pragma unroll
    for (int d = 1; d < 64; d <<= 1) {
        s += __shfl_xor(s, d, 64);
        q += __shfl_xor(q, d, 64);
    }
    __shared__ float ss[4], sq[4];
    const int wv = tid >> 6;
    if ((tid & 63) == 0) { ss[wv] = s; sq[wv] = q; }
    __syncthreads();
    s = ss[0] + ss[1] + ss[2] + ss[3];
    q = sq[0] + sq[1] + sq[2] + sq[3];
    const float mu = s * (1.0f / 1024.0f);
    const float var = q * (1.0f / 1024.0f) - mu * mu;
    const float rs = rsqrtf(var + 1e-5f);
    const int c = tid * 4;
    ushort4 o;
    o.x = f2bf((v.x - mu) * rs * g[c + 0] + bb[c + 0]);
    o.y = f2bf((v.y - mu) * rs * g[c + 1] + bb[c + 1]);
    o.z = f2bf((v.z - mu) * rs * g[c + 2] + bb[c + 2]);
    o.w = f2bf((v.w - mu) * rs * g[c + 3] + bb[c + 3]);
    *(ushort4*)&out[(size_t)row * 1024 + c] = o;
}

// ---------------- GEMM v5: quarter-granular counted pipeline ----------------
// (unchanged from R6 except MODE 2 epilogue uses inlined gelu_exact)

#define LGKM0                                            \
    asm volatile("s_waitcnt lgkmcnt(0)" ::: "memory");   \
    __builtin_amdgcn_sched_barrier(0)
#define VMC(n)                                           \
    asm volatile("s_waitcnt vmcnt(" #n ")" ::: "memory");\
    __builtin_amdgcn_sched_barrier(0)
#define PRIO_MFMA(mh)                                    \
    __builtin_amdgcn_s_setprio(1);                       \
    mf16(mh);                                            \
    __builtin_amdgcn_s_setprio(0);                       \
    __builtin_amdgcn_sched_barrier(0)

template <int MODE, int BN>
__global__ __launch_bounds__(512, 2) void gemmp(const unsigned short* __restrict__ A,
                                                const unsigned short* __restrict__ Bw,
                                                void* __restrict__ Out,
                                                const float* __restrict__ bias,
                                                const float* __restrict__ res,
                                                int M, int N, int K, int gn) {
    constexpr int WN = BN / 64, WM = 8 / WN, MFM = 256 / WM / 16;
    constexpr int AQ = 256 * 32;   // A quarter (ushorts)
    constexpr int BQ = BN * 32;    // B quarter
    constexpr int BUF = 2 * AQ + 2 * BQ;
    __shared__ unsigned short lds[2 * BUF];

    const int tid = threadIdx.x;
    const int l = tid & 63, w = tid >> 6;
    const int nwg = gridDim.x;
    const int sw = (blockIdx.x & 7) * (nwg >> 3) + (blockIdx.x >> 3);  // XCD swizzle
    const int m0 = (sw / gn) * 256;
    const int n0 = (sw % gn) * BN;
    const int wm = w / WN, wn = w % WN;
    const int fr = l & 15, kg = l >> 4;
    const int sgq = ((l & 3) - ((l >> 3) & 3)) & 3;  // inverse slot rotation (global side)
    const int srow = l >> 2;                          // row-in-16 for staging

    f32x4 acc[MFM][4] = {};
    bf16x8 afr[4], bfr[4];

    auto stA = [&](int bufi, int kk, int k0) {
#pragma unroll
        for (int j = 0; j < 2; ++j) {
            const int rb = w * 32 + j * 16;
            gload_lds16(A + (size_t)(m0 + rb + srow) * K + k0 + kk * 32 + sgq * 8,
                        lds + bufi * BUF + kk * AQ + rb * 32);
        }
    };
    auto stB = [&](int bufi, int kk, int k0) {
        if constexpr (BN == 256) {
#pragma unroll
            for (int j = 0; j < 2; ++j) {
                const int rb = w * 32 + j * 16;
                gload_lds16(Bw + (size_t)(n0 + rb + srow) * K + k0 + kk * 32 + sgq * 8,
                            lds + bufi * BUF + 2 * AQ + kk * BQ + rb * 32);
            }
        } else {
            const int rb = w * 16;
            gload_lds16(Bw + (size_t)(n0 + rb + srow) * K + k0 + kk * 32 + sgq * 8,
                        lds + bufi * BUF + 2 * AQ + kk * BQ + rb * 32);
        }
    };
    auto rdA = [&](int bufi, int kk, int mh) {
        const unsigned short* base = lds + bufi * BUF + kk * AQ;
#pragma unroll
        for (int i = 0; i < 4; ++i) {
            const int r = wm * (MFM * 16) + (mh * 4 + i) * 16 + fr;
            afr[i] = *(const bf16x8*)(base + r * 32 + (((kg + ((r >> 1) & 3)) & 3) * 8));
        }
    };
    auto rdB = [&](int bufi, int kk) {
        const unsigned short* base = lds + bufi * BUF + 2 * AQ + kk * BQ;
#pragma unroll
        for (int nt = 0; nt < 4; ++nt) {
            const int r = wn * 64 + nt * 16 + fr;
            bfr[nt] = *(const bf16x8*)(base + r * 32 + (((kg + ((r >> 1) & 3)) & 3) * 8));
        }
    };
    auto mf16 = [&](int mh) {
#pragma unroll
        for (int i = 0; i < 4; ++i)
#pragma unroll
            for (int nt = 0; nt < 4; ++nt)
                acc[mh * 4 + i][nt] = __builtin_amdgcn_mfma_f32_16x16x32_bf16(
                    bfr[nt], afr[i], acc[mh * 4 + i][nt], 0, 0, 0);
    };

    const int NT = K >> 6;
    int cur = 0;
    stB(0, 0, 0); stA(0, 0, 0); stB(0, 1, 0); stA(0, 1, 0);
    if constexpr (BN == 256) { VMC(4); } else { VMC(3); }
    __builtin_amdgcn_s_barrier();

    for (int t = 0; t < NT - 1; ++t) {
        const int nb = cur ^ 1;
        const int nk0 = (t + 1) << 6;
        if constexpr (BN == 256) {
            stB(nb, 0, nk0); rdA(cur, 0, 0); rdB(cur, 0);
            LGKM0; PRIO_MFMA(0); VMC(6); __builtin_amdgcn_s_barrier();
            stA(nb, 0, nk0); rdA(cur, 0, 1); rdB(cur, 0);
            LGKM0; PRIO_MFMA(1); VMC(4); __builtin_amdgcn_s_barrier();
            stB(nb, 1, nk0); rdA(cur, 1, 0); rdB(cur, 1);
            LGKM0; PRIO_MFMA(0); VMC(6); __builtin_amdgcn_s_barrier();
            stA(nb, 1, nk0); rdA(cur, 1, 1); rdB(cur, 1);
            LGKM0; PRIO_MFMA(1); VMC(4); __builtin_amdgcn_s_barrier();
        } else {
            stB(nb, 0, nk0); stA(nb, 0, nk0); rdA(cur, 0, 0); rdB(cur, 0);
            LGKM0; PRIO_MFMA(0); VMC(3); __builtin_amdgcn_s_barrier();
            stB(nb, 1, nk0); stA(nb, 1, nk0); rdA(cur, 1, 0); rdB(cur, 1);
            LGKM0; PRIO_MFMA(0); VMC(3); __builtin_amdgcn_s_barrier();
        }
        cur ^= 1;
    }
    if constexpr (BN == 256) {
        rdA(cur, 0, 0); rdB(cur, 0); LGKM0; PRIO_MFMA(0);
        rdA(cur, 0, 1);              LGKM0; PRIO_MFMA(1);
        VMC(0); __builtin_amdgcn_s_barrier();
        rdA(cur, 1, 0); rdB(cur, 1); LGKM0; PRIO_MFMA(0);
        rdA(cur, 1, 1);              LGKM0; PRIO_MFMA(1);
    } else {
        rdA(cur, 0, 0); rdB(cur, 0); LGKM0; PRIO_MFMA(0);
        VMC(0); __builtin_amdgcn_s_barrier();
        rdA(cur, 1, 0); rdB(cur, 1); LGKM0; PRIO_MFMA(0);
    }

    // Epilogue: lane (fr,kg) reg r holds C[m = base+mt*16+fr][n = base+nt*16+kg*4+r]
    const int cq = kg * 4;
#pragma unroll
    for (int mt = 0; mt < MFM; ++mt) {
        const int row = m0 + wm * (MFM * 16) + mt * 16 + fr;
#pragma unroll
        for (int nt = 0; nt < 4; ++nt) {
            const int col = n0 + wn * 64 + nt * 16 + cq;
            const f32x4 a = acc[mt][nt];
            if (MODE == 0) {
                ushort4 o;
                o.x = f2bf(a[0]); o.y = f2bf(a[1]); o.z = f2bf(a[2]); o.w = f2bf(a[3]);
                *(ushort4*)&((unsigned short*)Out)[(size_t)row * N + col] = o;
            } else if (MODE == 1) {
                const float4 bi = *(const float4*)&bias[col];
                const float4 re = *(const float4*)&res[(size_t)row * N + col];
                float4 o;
                o.x = a[0] + bi.x + re.x; o.y = a[1] + bi.y + re.y;
                o.z = a[2] + bi.z + re.z; o.w = a[3] + bi.w + re.w;
                *(float4*)&((float*)Out)[(size_t)row * N + col] = o;
            } else {
                const float4 bi = *(const float4*)&bias[col];
                ushort4 o;
                o.x = f2bf(gelu_exact(a[0] + bi.x));
                o.y = f2bf(gelu_exact(a[1] + bi.y));
                o.z = f2bf(gelu_exact(a[2] + bi.z));
                o.w = f2bf(gelu_exact(a[3] + bi.w));
                *(ushort4*)&((unsigned short*)Out)[(size_t)row * N + col] = o;
            }
        }
    }
}

// ---------------- Flash attention (unchanged) ----------------
__global__ __launch_bounds__(256) void attn_kernel(const unsigned short* __restrict__ qkv,
                                                   const int* __restrict__ length,
                                                   unsigned short* __restrict__ y) {
    const int id2 = (blockIdx.x & 7) * 256 + (blockIdx.x >> 3);
    const int qt = id2 & 15;
    const int h = (id2 >> 4) & 15;
    const int b = id2 >> 8;
    const int tid = threadIdx.x, lane = tid & 63, w = tid >> 6;
    const int q0 = qt * 64;
    const int len = length[b];
    const int ntiles = (len + 63) >> 6;

    __shared__ unsigned short Ks[64 * 64];
    __shared__ unsigned short Vs[64 * 64];
    __shared__ unsigned short Ps[4 * 16 * 64];

    const int fr = lane & 15, kg = lane >> 4;

    bf16x8 qf[2];
    {
        const unsigned short* qb = qkv + (size_t)(b * Nn + q0 + w * 16 + fr) * 3072 + h * 64 + kg * 8;
        qf[0] = *(const bf16x8*)(qb);
        qf[1] = *(const bf16x8*)(qb + 32);
    }

    float m[4] = {-1e30f, -1e30f, -1e30f, -1e30f};
    float lsum[4] = {0.f, 0.f, 0.f, 0.f};
    f32x4 accO[4] = {};

    const int krow_l = lane >> 3;
    const int kslot = lane & 7;
    const int vk0 = (tid >> 3) * 2;
    const int vd0 = (tid & 7) * 8;
    const unsigned short* vbase = qkv + (size_t)(b * Nn) * 3072 + 2048 + h * 64 + vd0;

    for (int t = 0; t < ntiles; ++t) {
        const int kv0 = t << 6;
#pragma unroll
        for (int c = 0; c < 2; ++c) {
            const int k = c * 32 + w * 8 + krow_l;
            const int ss = kslot ^ ((k ^ (k >> 3)) & 7);
            gload_lds16(qkv + (size_t)(b * Nn + kv0 + k) * 3072 + 1024 + h * 64 + ss * 8,
                        &Ks[(c * 32 + w * 8) * 64]);
        }
        {
            uint4 v0 = *(const uint4*)(vbase + (size_t)(kv0 + vk0) * 3072);
            uint4 v1 = *(const uint4*)(vbase + (size_t)(kv0 + vk0 + 1) * 3072);
            const unsigned* a0 = (const unsigned*)&v0;
            const unsigned* a1 = (const unsigned*)&v1;
#pragma unroll
            for (int i = 0; i < 8; ++i) {
                const unsigned lo = (a0[i >> 1] >> ((i & 1) * 16)) & 0xffffu;
                const unsigned hi = (a1[i >> 1] >> ((i & 1) * 16)) & 0xffffu;
                const int d = vd0 + i;
                const int off = (d * 128 + vk0 * 2) ^ (((d ^ (d >> 3)) & 7) << 4);
                *(unsigned*)((char*)Vs + off) = lo | (hi << 16);
            }
        }
        __syncthreads();

        f32x4 accS[4] = {};
#pragma unroll
        for (int nt = 0; nt < 4; ++nt) {
            const int kr = nt * 16 + fr;
            const int swz = ((kr ^ (kr >> 3)) & 7) << 4;
#pragma unroll
            for (int kt = 0; kt < 2; ++kt) {
                bf16x8 kf = *(const bf16x8*)((const char*)Ks + ((kr * 128 + (kt * 32 + kg * 8) * 2) ^ swz));
                accS[nt] = __builtin_amdgcn_mfma_f32_16x16x32_bf16(qf[kt], kf, accS[nt], 0, 0, 0);
            }
        }

        float p[4][4], sc[4];
#pragma unroll
        for (int r = 0; r < 4; ++r) {
            float sv[4];
            float mx = -1e30f;
#pragma unroll
            for (int nt = 0; nt < 4; ++nt) {
                sv[nt] = accS[nt][r] * SCALEf + ((kv0 + nt * 16 + fr >= len) ? -10000.0f : 0.0f);
                mx = fmaxf(mx, sv[nt]);
            }
#pragma unroll
            for (int d = 1; d < 16; d <<= 1) mx = fmaxf(mx, __shfl_xor(mx, d, 64));
            const float mnew = fmaxf(m[r], mx);
            sc[r] = __expf(m[r] - mnew);
            float rsum = 0.f;
#pragma unroll
            for (int nt = 0; nt < 4; ++nt) {
                p[nt][r] = __expf(sv[nt] - mnew);
                rsum += p[nt][r];
            }
#pragma unroll
            for (int d = 1; d < 16; d <<= 1) rsum += __shfl_xor(rsum, d, 64);
            lsum[r] = lsum[r] * sc[r] + rsum;
            m[r] = mnew;
        }
#pragma unroll
        for (int nd = 0; nd < 4; ++nd)
#pragma unroll
            for (int r = 0; r < 4; ++r) accO[nd][r] *= sc[r];

#pragma unroll
        for (int r = 0; r < 4; ++r) {
            const int q = kg * 4 + r;
            const int swz = ((q ^ (q >> 3)) & 7) << 4;
#pragma unroll
            for (int nt = 0; nt < 4; ++nt) {
                const int kk = nt * 16 + fr;
                *(unsigned short*)((char*)Ps + ((w * 2048 + q * 128 + kk * 2) ^ swz)) = f2bf(p[nt][r]);
            }
        }
        __builtin_amdgcn_wave_barrier();

        const int swzp = ((fr ^ (fr >> 3)) & 7) << 4;
#pragma unroll
        for (int kt = 0; kt < 2; ++kt) {
            bf16x8 pf = *(const bf16x8*)((const char*)Ps +
                        ((w * 2048 + fr * 128 + (kt * 32 + kg * 8) * 2) ^ swzp));
#pragma unroll
            for (int nd = 0; nd < 4; ++nd) {
                const int d = nd * 16 + fr;
                const int swzv = ((d ^ (d >> 3)) & 7) << 4;
                bf16x8 vf = *(const bf16x8*)((const char*)Vs +
                            ((d * 128 + (kt * 32 + kg * 8) * 2) ^ swzv));
                accO[nd] = __builtin_amdgcn_mfma_f32_16x16x32_bf16(pf, vf, accO[nd], 0, 0, 0);
            }
        }
        __syncthreads();
    }

#pragma unroll
    for (int r = 0; r < 4; ++r) {
        const float inv = 1.0f / lsum[r];
        const int row = q0 + w * 16 + kg * 4 + r;
#pragma unroll
        for (int nd = 0; nd < 4; ++nd)
            y[(size_t)(b * Nn + row) * 1024 + h * 64 + nd * 16 + fr] = f2bf(accO[nd][r] * inv);
    }
}

// ---------------- launch ----------------
extern "C" void kernel_launch(void* const* d_in, const int* in_sizes, int n_in,
                              void* d_out, int out_size, void* d_ws, size_t ws_size,
                              hipStream_t stream) {
    (void)in_sizes; (void)n_in; (void)out_size; (void)ws_size;
    const float* x     = (const float*)d_in[0];
    const int*   len   = (const int*)d_in[1];
    const float* g1    = (const float*)d_in[2];
    const float* b1    = (const float*)d_in[3];
    const float* Wqkv  = (const float*)d_in[4];
    const float* Wproj = (const float*)d_in[5];
    const float* bproj = (const float*)d_in[6];
    const float* g2    = (const float*)d_in[7];
    const float* b2    = (const float*)d_in[8];
    const float* W1    = (const float*)d_in[9];
    const float* bb1   = (const float*)d_in[10];
    const float* W2    = (const float*)d_in[11];
    const float* bb2   = (const float*)d_in[12];
    float* out = (float*)d_out;

    char* ws = (char*)d_ws;
    size_t off = 0;
    auto alloc = [&](size_t bytes) {
        void* p = ws + off;
        off += (bytes + 255) & ~(size_t)255;
        return p;
    };
    unsigned short* xn  = (unsigned short*)alloc(8192ULL * 1024 * 2);
    unsigned short* qkv = (unsigned short*)alloc(8192ULL * 3072 * 2);
    unsigned short* yb  = (unsigned short*)alloc(8192ULL * 1024 * 2);
    float* x2           = (float*)alloc(8192ULL * 1024 * 4);
    unsigned short* wqkv_b  = (unsigned short*)alloc(3072ULL * 1024 * 2);
    unsigned short* wproj_b = (unsigned short*)alloc(1024ULL * 1024 * 2);
    unsigned short* w1_b    = (unsigned short*)alloc(4096ULL * 1024 * 2);
    unsigned short* w2_b    = (unsigned short*)alloc(1024ULL * 4096 * 2);
    unsigned short* hb = qkv;  // reuse: qkv+yb dead by MLP1

    cvt_bf16<<<3072 * 1024 / 4 / 256, 256, 0, stream>>>(Wqkv, wqkv_b, 3072 * 1024 / 4);
    cvt_bf16<<<1024 * 1024 / 4 / 256, 256, 0, stream>>>(Wproj, wproj_b, 1024 * 1024 / 4);
    cvt_bf16<<<4096 * 1024 / 4 / 256, 256, 0, stream>>>(W1, w1_b, 4096 * 1024 / 4);
    cvt_bf16<<<4096 * 1024 / 4 / 256, 256, 0, stream>>>(W2, w2_b, 4096 * 1024 / 4);

    ln_kernel<<<8192, 256, 0, stream>>>(x, g1, b1, xn);
    gemmp<0, 128><<<768, 512, 0, stream>>>(xn, wqkv_b, qkv, nullptr, nullptr, 8192, 3072, 1024, 24);
    attn_kernel<<<2048, 256, 0, stream>>>(qkv, len, yb);
    gemmp<1, 128><<<256, 512, 0, stream>>>(yb, wproj_b, x2, bproj, x, 8192, 1024, 1024, 8);
    ln_kernel<<<8192, 256, 0, stream>>>(x2, g2, b2, xn);
    gemmp<2, 256><<<512, 512, 0, stream>>>(xn, w1_b, hb, bb1, nullptr, 8192, 4096, 1024, 16);
    gemmp<1, 128><<<256, 512, 0, stream>>>(hb, w2_b, out, bb2, x2, 8192, 1024, 4096, 8);
}